// Round 7
// baseline (232.435 us; speedup 1.0000x reference)
//
#include <hip/hip_runtime.h>
#include <hip/hip_bf16.h>

// GroupLinear: out[t] = x[t] @ w[gid(t)].T
// T=8192, G=8, K=1024, N=2048; groups = contiguous token ranges (cum end-offs).
//
// R12 = R5 restored EXACTLY (best measured: GEMM 54us, total 184.0us), with a
// single fail-safe change: __launch_bounds__(256, 5) on the GEMM.
//  - 5 blocks/CU x 32KiB LDS = exactly the 160KiB pool; VGPR cap 512/5=102
//    (kernel uses 64 -> no spill). If the HW packs the 5th block: all 1152
//    blocks co-resident (231 CUs), the 128-block straggler tail of the
//    4/CU config disappears, and TLP rises 16->20 waves/CU (m114 overlap
//    carries this 2-barrier structure). If it can't pack: identical to R5.
//  - Pipeline attempts R6/R9/R11 (counted-vmcnt, 3 derivations) all regressed
//    (72-81us vs 54): TLP-for-ILP trade loses at K=16 tiles. Abandoned.
//  - R10's LDS-transpose epilogue regressed (bank conflicts 0->262K). Reverted.
//  - XCD swizzle cut FETCH 84->43MB across R6/R8/R10 but never moved time
//    (GEMM is not traffic-bound); omitted to keep this round single-variable.

#define T_DIM 8192
#define G_DIM 8
#define K_DIM 1024
#define N_DIM 2048
#define MAX_PAIRS 72  // 64 m-tiles + <=7 boundary duplicates, rounded up

using short8  = __attribute__((ext_vector_type(8))) short;   // 8 bf16
using f32x4   = __attribute__((ext_vector_type(4))) float;   // MFMA acc / nt loads
using ushort8 = __attribute__((ext_vector_type(8))) unsigned short;

typedef __attribute__((address_space(1))) void gvoid;  // global
typedef __attribute__((address_space(3))) void lvoid;  // LDS

// ---------------- fp32 -> bf16 convert (grid-stride, 2x unroll, nt loads) ---
__global__ __launch_bounds__(256) void cvt_kernel(const float* __restrict__ x,
                                                  const float* __restrict__ w,
                                                  ushort8* __restrict__ xb,
                                                  ushort8* __restrict__ wb,
                                                  int n8x, int n8tot) {
  const int stride = gridDim.x * blockDim.x;
  for (int i = blockIdx.x * blockDim.x + threadIdx.x; i < n8tot; i += 2 * stride) {
#pragma unroll
    for (int u = 0; u < 2; ++u) {
      const int idx = i + u * stride;
      if (idx >= n8tot) break;
      const f32x4* s; ushort8* d; int j;
      if (idx < n8x) { s = (const f32x4*)x; d = xb; j = idx; }
      else           { s = (const f32x4*)w; d = wb; j = idx - n8x; }
      f32x4 v0 = __builtin_nontemporal_load(&s[2 * j]);
      f32x4 v1 = __builtin_nontemporal_load(&s[2 * j + 1]);
      ushort8 o;
      o[0] = __builtin_bit_cast(unsigned short, __float2bfloat16(v0[0]));
      o[1] = __builtin_bit_cast(unsigned short, __float2bfloat16(v0[1]));
      o[2] = __builtin_bit_cast(unsigned short, __float2bfloat16(v0[2]));
      o[3] = __builtin_bit_cast(unsigned short, __float2bfloat16(v0[3]));
      o[4] = __builtin_bit_cast(unsigned short, __float2bfloat16(v1[0]));
      o[5] = __builtin_bit_cast(unsigned short, __float2bfloat16(v1[1]));
      o[6] = __builtin_bit_cast(unsigned short, __float2bfloat16(v1[2]));
      o[7] = __builtin_bit_cast(unsigned short, __float2bfloat16(v1[3]));
      d[j] = o;
    }
  }
}

// ---------------- grouped bf16 GEMM, compacted (expert, m-tile) pairs ------
__global__ __launch_bounds__(256, 5) void grouped_gemm_kernel(
    const __hip_bfloat16* __restrict__ xb,
    const __hip_bfloat16* __restrict__ wb,
    const int* __restrict__ offs,
    float* __restrict__ out) {
  // ---- map blockIdx.y -> (expert g, m-tile) via prefix sum of tile spans
  int offv[G_DIM];
#pragma unroll
  for (int i = 0; i < G_DIM; ++i) offv[i] = offs[i];

  const int p = blockIdx.y;
  int g = -1, tile = 0, lo = 0, hi = 0, pre = 0;
#pragma unroll
  for (int gi = 0; gi < G_DIM; ++gi) {
    const int l = gi ? offv[gi - 1] : 0;
    const int h = offv[gi];
    const int t0 = l >> 7;
    const int cnt = (h > l) ? (((h + 127) >> 7) - t0) : 0;
    if (g < 0 && p < pre + cnt) { g = gi; tile = t0 + (p - pre); lo = l; hi = h; }
    pre += cnt;
  }
  if (g < 0) return;  // p >= total pairs (few dead blocks)

  const int m0 = tile * 128;
  const int n0 = blockIdx.x * 128;

  __shared__ __align__(16) __hip_bfloat16 As[128 * 64];  // [m][k] swizzled
  __shared__ __align__(16) __hip_bfloat16 Bs[128 * 64];  // [n][k] swizzled

  const __hip_bfloat16* wg = wb + (size_t)g * N_DIM * K_DIM;

  const int lane = threadIdx.x & 63;
  const int wid  = threadIdx.x >> 6;
  const int wm   = wid >> 1;   // wave row (0..1)
  const int wn   = wid & 1;    // wave col (0..1)

  // staging: chunk j = 8 rows x 64 cols = 1KB; lane l -> LDS base + l*16B.
  // row&7 == srow, so the XOR swizzle permutes the GLOBAL column block.
  const int srow = lane >> 3;                  // row within chunk
  const int scol = ((lane & 7) ^ srow) * 8;    // swizzled global col (elems)

  f32x4 acc[4][4] = {};

  for (int kk = 0; kk < K_DIM / 64; ++kk) {
    const int k0 = kk * 64;
#pragma unroll
    for (int i = 0; i < 4; ++i) {
      const int j   = wid * 4 + i;      // 0..15
      const int row = j * 8 + srow;
      const __hip_bfloat16* ga = xb + (size_t)(m0 + row) * K_DIM + k0 + scol;
      const __hip_bfloat16* gb = wg + (size_t)(n0 + row) * K_DIM + k0 + scol;
      __builtin_amdgcn_global_load_lds((gvoid*)ga, (lvoid*)(As + j * 512), 16, 0, 0);
      __builtin_amdgcn_global_load_lds((gvoid*)gb, (lvoid*)(Bs + j * 512), 16, 0, 0);
    }
    __syncthreads();

#pragma unroll
    for (int ks = 0; ks < 2; ++ks) {
      // global 16B-block index this lane needs: kb = ks*4 + (lane>>4)
      // fragment rows have row&7 == lane&7 -> swizzled offset:
      const int kb  = ks * 4 + (lane >> 4);
      const int off = ((kb ^ (lane & 7)) * 8);
      short8 a[4], b[4];
#pragma unroll
      for (int mt = 0; mt < 4; ++mt)
        a[mt] = *reinterpret_cast<const short8*>(
            As + (wm * 64 + mt * 16 + (lane & 15)) * 64 + off);
#pragma unroll
      for (int nt = 0; nt < 4; ++nt)
        b[nt] = *reinterpret_cast<const short8*>(
            Bs + (wn * 64 + nt * 16 + (lane & 15)) * 64 + off);
#pragma unroll
      for (int mt = 0; mt < 4; ++mt)
#pragma unroll
        for (int nt = 0; nt < 4; ++nt)
          acc[mt][nt] = __builtin_amdgcn_mfma_f32_16x16x32_bf16(
              a[mt], b[nt], acc[mt][nt], 0, 0, 0);
    }
    __syncthreads();
  }

  // epilogue: C/D layout col=lane&15, row=(lane>>4)*4+reg [m89-verified];
  // store only rows in [lo,hi) — boundary tiles written disjointly per expert.
  const int quad = lane >> 4;
#pragma unroll
  for (int mt = 0; mt < 4; ++mt) {
    const int rbase = m0 + wm * 64 + mt * 16 + quad * 4;
#pragma unroll
    for (int r = 0; r < 4; ++r) {
      const int row = rbase + r;
      if (row < lo || row >= hi) continue;
#pragma unroll
      for (int nt = 0; nt < 4; ++nt) {
        const int col = n0 + wn * 64 + nt * 16 + (lane & 15);
        out[(size_t)row * N_DIM + col] = acc[mt][nt][r];
      }
    }
  }
}

// ---------------- fp32 fallback (only if d_ws < 48 MB; correctness-only) ----
__global__ __launch_bounds__(256) void fallback_kernel(
    const float* __restrict__ x, const float* __restrict__ w,
    const int* __restrict__ offs, float* __restrict__ out) {
  __shared__ float xs[K_DIM];
  const int t = blockIdx.y;
  int g = 0;
  while (g < G_DIM - 1 && offs[g] <= t) ++g;
  for (int i = threadIdx.x; i < K_DIM; i += blockDim.x)
    xs[i] = x[(size_t)t * K_DIM + i];
  __syncthreads();
  const int n = blockIdx.x * blockDim.x + threadIdx.x;
  const float* wr = w + ((size_t)g * N_DIM + n) * K_DIM;
  float s = 0.f;
  for (int k = 0; k < K_DIM; ++k) s += xs[k] * wr[k];
  out[(size_t)t * N_DIM + n] = s;
}

extern "C" void kernel_launch(void* const* d_in, const int* in_sizes, int n_in,
                              void* d_out, int out_size, void* d_ws, size_t ws_size,
                              hipStream_t stream) {
  const float* x    = (const float*)d_in[0];
  const float* w    = (const float*)d_in[1];
  const int*   offs = (const int*)d_in[2];
  float*       out  = (float*)d_out;

  const size_t x_elems = (size_t)T_DIM * K_DIM;            // 8.39M
  const size_t w_elems = (size_t)G_DIM * N_DIM * K_DIM;    // 16.78M
  const size_t need    = (x_elems + w_elems) * sizeof(__hip_bfloat16);  // 48 MiB

  if (ws_size < need) {
    fallback_kernel<<<dim3(N_DIM / 256, T_DIM), 256, 0, stream>>>(x, w, offs, out);
    return;
  }

  __hip_bfloat16* xb = (__hip_bfloat16*)d_ws;
  __hip_bfloat16* wb = xb + x_elems;

  const int n8x   = (int)(x_elems / 8);              // 1,048,576
  const int n8tot = (int)((x_elems + w_elems) / 8);  // 3,145,728
  cvt_kernel<<<4096, 256, 0, stream>>>(x, w, (ushort8*)xb, (ushort8*)wb,
                                       n8x, n8tot);

  grouped_gemm_kernel<<<dim3(N_DIM / 128, MAX_PAIRS), 256, 0, stream>>>(
      xb, wb, offs, out);
}

// Round 8
// 186.352 us; speedup vs baseline: 1.2473x; 1.2473x over previous
//
#include <hip/hip_runtime.h>
#include <hip/hip_bf16.h>

// GroupLinear: out[t] = x[t] @ w[gid(t)].T
// T=8192, G=8, K=1024, N=2048; groups = contiguous token ranges (cum end-offs).
//
// R13 = R5's GEMM restored BYTE-IDENTICAL (best measured: GEMM 54us, total
// 184.0us) + branch-free cvt (the only dispatch never yet tuned):
//  - cvt: two separate grid-stride loops (X then W) instead of a per-item
//    idx<n8x select -> removes cmp/cndmask/pointer-select per item; same
//    16B nt loads + 16B stores, 2x unroll. ~30us @ 5.0 TB/s -> target ~26us.
//  - GEMM: R5 exact. Closed levers (measured this session):
//    * launch_bounds(256,5): compiler re-budget -> VGPR 60->48, acc spills,
//      GEMM 99us (R12). Keep (256,4).
//    * counted-vmcnt pipelines (R6/R9/R11, 3 independent derivations):
//      72-81us — TLP-for-ILP loses at K=16 tiles. Abandoned.
//    * XCD swizzles: FETCH 84->43MB, time-neutral (not traffic-bound).
//    * LDS-transpose epilogue (R10): bank conflicts 0->262K, +7us.
//    * fused W-cvt in GEMM (R7): 2x logical stream, L2 thrash, 123us.

#define T_DIM 8192
#define G_DIM 8
#define K_DIM 1024
#define N_DIM 2048
#define MAX_PAIRS 72  // 64 m-tiles + <=7 boundary duplicates, rounded up

using short8  = __attribute__((ext_vector_type(8))) short;   // 8 bf16
using f32x4   = __attribute__((ext_vector_type(4))) float;   // MFMA acc / nt loads
using ushort8 = __attribute__((ext_vector_type(8))) unsigned short;

typedef __attribute__((address_space(1))) void gvoid;  // global
typedef __attribute__((address_space(3))) void lvoid;  // LDS

// ---------------- fp32 -> bf16 convert (branch-free: X loop then W loop) ----
__device__ __forceinline__ ushort8 cvt8(f32x4 v0, f32x4 v1) {
  ushort8 o;
  o[0] = __builtin_bit_cast(unsigned short, __float2bfloat16(v0[0]));
  o[1] = __builtin_bit_cast(unsigned short, __float2bfloat16(v0[1]));
  o[2] = __builtin_bit_cast(unsigned short, __float2bfloat16(v0[2]));
  o[3] = __builtin_bit_cast(unsigned short, __float2bfloat16(v0[3]));
  o[4] = __builtin_bit_cast(unsigned short, __float2bfloat16(v1[0]));
  o[5] = __builtin_bit_cast(unsigned short, __float2bfloat16(v1[1]));
  o[6] = __builtin_bit_cast(unsigned short, __float2bfloat16(v1[2]));
  o[7] = __builtin_bit_cast(unsigned short, __float2bfloat16(v1[3]));
  return o;
}

__global__ __launch_bounds__(256) void cvt_kernel(const float* __restrict__ x,
                                                  const float* __restrict__ w,
                                                  ushort8* __restrict__ xb,
                                                  ushort8* __restrict__ wb,
                                                  int n8x, int n8w) {
  const int stride = gridDim.x * blockDim.x;
  const int tid    = blockIdx.x * blockDim.x + threadIdx.x;

  const f32x4* xs = (const f32x4*)x;
  for (int i = tid; i < n8x; i += 2 * stride) {
    f32x4 a0 = __builtin_nontemporal_load(&xs[2 * i]);
    f32x4 a1 = __builtin_nontemporal_load(&xs[2 * i + 1]);
    const int j = i + stride;
    if (j < n8x) {
      f32x4 b0 = __builtin_nontemporal_load(&xs[2 * j]);
      f32x4 b1 = __builtin_nontemporal_load(&xs[2 * j + 1]);
      xb[i] = cvt8(a0, a1);
      xb[j] = cvt8(b0, b1);
    } else {
      xb[i] = cvt8(a0, a1);
    }
  }

  const f32x4* ws = (const f32x4*)w;
  for (int i = tid; i < n8w; i += 2 * stride) {
    f32x4 a0 = __builtin_nontemporal_load(&ws[2 * i]);
    f32x4 a1 = __builtin_nontemporal_load(&ws[2 * i + 1]);
    const int j = i + stride;
    if (j < n8w) {
      f32x4 b0 = __builtin_nontemporal_load(&ws[2 * j]);
      f32x4 b1 = __builtin_nontemporal_load(&ws[2 * j + 1]);
      wb[i] = cvt8(a0, a1);
      wb[j] = cvt8(b0, b1);
    } else {
      wb[i] = cvt8(a0, a1);
    }
  }
}

// ---------------- grouped bf16 GEMM, compacted (expert, m-tile) pairs ------
__global__ __launch_bounds__(256, 4) void grouped_gemm_kernel(
    const __hip_bfloat16* __restrict__ xb,
    const __hip_bfloat16* __restrict__ wb,
    const int* __restrict__ offs,
    float* __restrict__ out) {
  // ---- map blockIdx.y -> (expert g, m-tile) via prefix sum of tile spans
  int offv[G_DIM];
#pragma unroll
  for (int i = 0; i < G_DIM; ++i) offv[i] = offs[i];

  const int p = blockIdx.y;
  int g = -1, tile = 0, lo = 0, hi = 0, pre = 0;
#pragma unroll
  for (int gi = 0; gi < G_DIM; ++gi) {
    const int l = gi ? offv[gi - 1] : 0;
    const int h = offv[gi];
    const int t0 = l >> 7;
    const int cnt = (h > l) ? (((h + 127) >> 7) - t0) : 0;
    if (g < 0 && p < pre + cnt) { g = gi; tile = t0 + (p - pre); lo = l; hi = h; }
    pre += cnt;
  }
  if (g < 0) return;  // p >= total pairs (few dead blocks)

  const int m0 = tile * 128;
  const int n0 = blockIdx.x * 128;

  __shared__ __align__(16) __hip_bfloat16 As[128 * 64];  // [m][k] swizzled
  __shared__ __align__(16) __hip_bfloat16 Bs[128 * 64];  // [n][k] swizzled

  const __hip_bfloat16* wg = wb + (size_t)g * N_DIM * K_DIM;

  const int lane = threadIdx.x & 63;
  const int wid  = threadIdx.x >> 6;
  const int wm   = wid >> 1;   // wave row (0..1)
  const int wn   = wid & 1;    // wave col (0..1)

  // staging: chunk j = 8 rows x 64 cols = 1KB; lane l -> LDS base + l*16B.
  // row&7 == srow, so the XOR swizzle permutes the GLOBAL column block.
  const int srow = lane >> 3;                  // row within chunk
  const int scol = ((lane & 7) ^ srow) * 8;    // swizzled global col (elems)

  f32x4 acc[4][4] = {};

  for (int kk = 0; kk < K_DIM / 64; ++kk) {
    const int k0 = kk * 64;
#pragma unroll
    for (int i = 0; i < 4; ++i) {
      const int j   = wid * 4 + i;      // 0..15
      const int row = j * 8 + srow;
      const __hip_bfloat16* ga = xb + (size_t)(m0 + row) * K_DIM + k0 + scol;
      const __hip_bfloat16* gb = wg + (size_t)(n0 + row) * K_DIM + k0 + scol;
      __builtin_amdgcn_global_load_lds((gvoid*)ga, (lvoid*)(As + j * 512), 16, 0, 0);
      __builtin_amdgcn_global_load_lds((gvoid*)gb, (lvoid*)(Bs + j * 512), 16, 0, 0);
    }
    __syncthreads();

#pragma unroll
    for (int ks = 0; ks < 2; ++ks) {
      // global 16B-block index this lane needs: kb = ks*4 + (lane>>4)
      // fragment rows have row&7 == lane&7 -> swizzled offset:
      const int kb  = ks * 4 + (lane >> 4);
      const int off = ((kb ^ (lane & 7)) * 8);
      short8 a[4], b[4];
#pragma unroll
      for (int mt = 0; mt < 4; ++mt)
        a[mt] = *reinterpret_cast<const short8*>(
            As + (wm * 64 + mt * 16 + (lane & 15)) * 64 + off);
#pragma unroll
      for (int nt = 0; nt < 4; ++nt)
        b[nt] = *reinterpret_cast<const short8*>(
            Bs + (wn * 64 + nt * 16 + (lane & 15)) * 64 + off);
#pragma unroll
      for (int mt = 0; mt < 4; ++mt)
#pragma unroll
        for (int nt = 0; nt < 4; ++nt)
          acc[mt][nt] = __builtin_amdgcn_mfma_f32_16x16x32_bf16(
              a[mt], b[nt], acc[mt][nt], 0, 0, 0);
    }
    __syncthreads();
  }

  // epilogue: C/D layout col=lane&15, row=(lane>>4)*4+reg [m89-verified];
  // store only rows in [lo,hi) — boundary tiles written disjointly per expert.
  const int quad = lane >> 4;
#pragma unroll
  for (int mt = 0; mt < 4; ++mt) {
    const int rbase = m0 + wm * 64 + mt * 16 + quad * 4;
#pragma unroll
    for (int r = 0; r < 4; ++r) {
      const int row = rbase + r;
      if (row < lo || row >= hi) continue;
#pragma unroll
      for (int nt = 0; nt < 4; ++nt) {
        const int col = n0 + wn * 64 + nt * 16 + (lane & 15);
        out[(size_t)row * N_DIM + col] = acc[mt][nt][r];
      }
    }
  }
}

// ---------------- fp32 fallback (only if d_ws < 48 MB; correctness-only) ----
__global__ __launch_bounds__(256) void fallback_kernel(
    const float* __restrict__ x, const float* __restrict__ w,
    const int* __restrict__ offs, float* __restrict__ out) {
  __shared__ float xs[K_DIM];
  const int t = blockIdx.y;
  int g = 0;
  while (g < G_DIM - 1 && offs[g] <= t) ++g;
  for (int i = threadIdx.x; i < K_DIM; i += blockDim.x)
    xs[i] = x[(size_t)t * K_DIM + i];
  __syncthreads();
  const int n = blockIdx.x * blockDim.x + threadIdx.x;
  const float* wr = w + ((size_t)g * N_DIM + n) * K_DIM;
  float s = 0.f;
  for (int k = 0; k < K_DIM; ++k) s += xs[k] * wr[k];
  out[(size_t)t * N_DIM + n] = s;
}

extern "C" void kernel_launch(void* const* d_in, const int* in_sizes, int n_in,
                              void* d_out, int out_size, void* d_ws, size_t ws_size,
                              hipStream_t stream) {
  const float* x    = (const float*)d_in[0];
  const float* w    = (const float*)d_in[1];
  const int*   offs = (const int*)d_in[2];
  float*       out  = (float*)d_out;

  const size_t x_elems = (size_t)T_DIM * K_DIM;            // 8.39M
  const size_t w_elems = (size_t)G_DIM * N_DIM * K_DIM;    // 16.78M
  const size_t need    = (x_elems + w_elems) * sizeof(__hip_bfloat16);  // 48 MiB

  if (ws_size < need) {
    fallback_kernel<<<dim3(N_DIM / 256, T_DIM), 256, 0, stream>>>(x, w, offs, out);
    return;
  }

  __hip_bfloat16* xb = (__hip_bfloat16*)d_ws;
  __hip_bfloat16* wb = xb + x_elems;

  const int n8x = (int)(x_elems / 8);  // 1,048,576
  const int n8w = (int)(w_elems / 8);  // 2,097,152
  cvt_kernel<<<4096, 256, 0, stream>>>(x, w, (ushort8*)xb, (ushort8*)wb,
                                       n8x, n8w);

  grouped_gemm_kernel<<<dim3(N_DIM / 128, MAX_PAIRS), 256, 0, stream>>>(
      xb, wb, offs, out);
}